// Round 8
// baseline (273.294 us; speedup 1.0000x reference)
//
#include <hip/hip_runtime.h>
#include <hip/hip_bf16.h>

typedef __attribute__((ext_vector_type(8))) short bf16x8;
typedef __attribute__((ext_vector_type(4))) float f32x4;

#define NQ 2500
#define NKK 6336
#define NHEADS 4
#define DHEAD 32
// SCALE * log2(e): p = exp2(s * c)
#define CSC 0.25503482f
#define BIGNEG (-1.0e30f)

// workspace byte offsets
#define WS_QP 0
#define WS_KP 640000
#define WS_VT 2262016
#define WS_WB 3884032
#define WS_OP 4146176
// Opart: per split 2500 rows x 136 floats (128 O + 4 l per head)
#define OSPLIT_F 340000
#define OROW_F 136
#define WS_REQ3 8226176ULL
#define WS_REQ4 9586176ULL
#define WS_REQ6 12306176ULL

// bf16 weight element offsets inside WS_WB
#define WQB 0
#define WKB 16384
#define WVB 32768
#define WPROJB 49152
#define W1B 65536
#define W2B 98304

#define NTILES_TOTAL 99
#define TQ 16
#define TK 64
#define QBLOCKS 157
#define MQBLOCKS 313

#define KSTR 136
#define VSTR 72
#define PSTR 72
#define ABSTR 68

__device__ __forceinline__ unsigned short bf16bits(float x) {
  union { __hip_bfloat16 h; unsigned short s; } cv;
  cv.h = __float2bfloat16(x);
  return cv.s;
}

// ============ weight fp32->bf16 conversion (once per launch) ============
__global__ __launch_bounds__(256) void wconv_kernel(
    const float* __restrict__ wq, const float* __restrict__ wk,
    const float* __restrict__ wv, const float* __restrict__ wproj,
    const float* __restrict__ w1, const float* __restrict__ w2,
    __hip_bfloat16* __restrict__ wb)
{
  int e = (blockIdx.x * 256 + threadIdx.x) * 4;
  const float* src; int off;
  if (e < 16384)      { src = wq;    off = e; }
  else if (e < 32768) { src = wk;    off = e - 16384; }
  else if (e < 49152) { src = wv;    off = e - 32768; }
  else if (e < 65536) { src = wproj; off = e - 49152; }
  else if (e < 98304) { src = w1;    off = e - 65536; }
  else                { src = w2;    off = e - 98304; }
  float4 v = *(const float4*)(src + off);
  ushort4 o4;
  o4.x = bf16bits(v.x); o4.y = bf16bits(v.y); o4.z = bf16bits(v.z); o4.w = bf16bits(v.w);
  *(ushort4*)((unsigned short*)wb + e) = o4;
}

// ============ lnproj: LN + 128x128 projection (MFMA), 32 rows/block, 256 thr ============
__global__ __launch_bounds__(256) void lnproj_kernel(
    const float* __restrict__ qin, const float* __restrict__ kin, const float* __restrict__ vin,
    const float* __restrict__ qn_g, const float* __restrict__ qn_b,
    const float* __restrict__ kn_g, const float* __restrict__ kn_b,
    const float* __restrict__ vn_g, const float* __restrict__ vn_b,
    const __hip_bfloat16* __restrict__ wball,
    const float* __restrict__ bq, const float* __restrict__ bk, const float* __restrict__ bv,
    __hip_bfloat16* __restrict__ Qp, __hip_bfloat16* __restrict__ Kp,
    __hip_bfloat16* __restrict__ Vt)
{
  __shared__ __hip_bfloat16 lxb[32][136];
  __shared__ float lpart[32][8][2];
  __shared__ float lmr[32][2];
  __shared__ float lgb[128], lbeb[128];

  const int t = threadIdx.x;
  const int bb = blockIdx.x;
  int mode, row0;
  const float *in, *g, *be, *bo;
  const __hip_bfloat16* wb;
  if (bb < 79)       { mode = 0; row0 = bb * 32;         in = qin; g = qn_g; be = qn_b; wb = wball + WQB; bo = bq; }
  else if (bb < 277) { mode = 1; row0 = (bb - 79) * 32;  in = kin; g = kn_g; be = kn_b; wb = wball + WKB; bo = bk; }
  else               { mode = 2; row0 = (bb - 277) * 32; in = vin; g = vn_g; be = vn_b; wb = wball + WVB; bo = bv; }

  if (t < 128) { lgb[t] = g[t]; lbeb[t] = be[t]; }

  const int row = t & 31, seg = t >> 5;   // 8 segs x 16 d each
  int grow = row0 + row;
  size_t base, dstr;
  bool rvalid = true;
  if (mode == 0) { rvalid = (grow < NQ); base = (size_t)(rvalid ? grow : NQ - 1); dstr = NQ; }
  else { int n = grow / 1056, rr = grow - n * 1056; base = (size_t)n * 135168 + rr; dstr = 1056; }

  float xr[16];
  float s = 0.f, ss = 0.f;
  #pragma unroll
  for (int i = 0; i < 16; ++i) {
    float x = in[base + (size_t)(seg * 16 + i) * dstr];
    xr[i] = x; s += x; ss += x * x;
  }
  lpart[row][seg][0] = s; lpart[row][seg][1] = ss;
  __syncthreads();
  if (t < 32) {
    float S = 0.f, SS = 0.f;
    #pragma unroll
    for (int j = 0; j < 8; ++j) { S += lpart[t][j][0]; SS += lpart[t][j][1]; }
    float mean = S * (1.f / 128.f);
    float var  = SS * (1.f / 128.f) - mean * mean;
    lmr[t][0] = mean;
    lmr[t][1] = rsqrtf(fmaxf(var, 0.f) + 1e-5f);
  }
  __syncthreads();
  {
    float mean = lmr[row][0], rstd = lmr[row][1];
    #pragma unroll
    for (int i = 0; i < 16; ++i) {
      int d = seg * 16 + i;
      lxb[row][d] = __float2bfloat16((xr[i] - mean) * rstd * lgb[d] + lbeb[d]);
    }
  }
  __syncthreads();

  // GEMM: 32 rows x 128 out, K=128; 4 waves, each 32-wide o-chunk
  const int wid = t >> 6, lane = t & 63;
  const int n16 = lane & 15, quad = lane >> 4;
  const int ow = wid * 32;

  f32x4 acc[2][2] = {};
  for (int kt = 0; kt < 4; ++kt) {
    bf16x8 af[2];
    #pragma unroll
    for (int mi = 0; mi < 2; ++mi)
      af[mi] = *(const bf16x8*)&lxb[mi * 16 + n16][kt * 32 + quad * 8];
    #pragma unroll
    for (int ni = 0; ni < 2; ++ni) {
      bf16x8 bw = *(const bf16x8*)(wb + (size_t)(ow + ni * 16 + n16) * 128 + kt * 32 + quad * 8);
      #pragma unroll
      for (int mi = 0; mi < 2; ++mi)
        acc[mi][ni] = __builtin_amdgcn_mfma_f32_16x16x32_bf16(af[mi], bw, acc[mi][ni], 0, 0, 0);
    }
  }

  float bias[2];
  #pragma unroll
  for (int ni = 0; ni < 2; ++ni) bias[ni] = bo[ow + ni * 16 + n16];

  #pragma unroll
  for (int mi = 0; mi < 2; ++mi) {
    int gr0 = row0 + mi * 16 + quad * 4;
    if (mode == 2) {
      #pragma unroll
      for (int ni = 0; ni < 2; ++ni) {
        int o = ow + ni * 16 + n16;
        ushort4 v4;
        v4.x = bf16bits(acc[mi][ni][0] + bias[ni]);
        v4.y = bf16bits(acc[mi][ni][1] + bias[ni]);
        v4.z = bf16bits(acc[mi][ni][2] + bias[ni]);
        v4.w = bf16bits(acc[mi][ni][3] + bias[ni]);
        *(ushort4*)((unsigned short*)Vt + (size_t)o * NKK + gr0) = v4;
      }
    } else {
      #pragma unroll
      for (int rg = 0; rg < 4; ++rg) {
        int gr = gr0 + rg;
        if (mode != 0 || gr < NQ) {
          #pragma unroll
          for (int ni = 0; ni < 2; ++ni) {
            int o = ow + ni * 16 + n16;
            __hip_bfloat16 b16 = __float2bfloat16(acc[mi][ni][rg] + bias[ni]);
            if (mode == 0) Qp[(size_t)gr * 128 + o] = b16;
            else           Kp[(size_t)gr * 128 + o] = b16;
          }
        }
      }
    }
  }
}

// ============ flash attention: fixed-base softmax (no cross-lane ops in K-loop) ============
__global__ __launch_bounds__(256, 3) void attn_kernel(
    const __hip_bfloat16* __restrict__ Qp,
    const __hip_bfloat16* __restrict__ Kp,
    const __hip_bfloat16* __restrict__ Vt,
    const float* __restrict__ Wl,
    const int* __restrict__ vis,
    float* __restrict__ Opart)
{
  __shared__ alignas(16) __hip_bfloat16 lk[TK * KSTR];          // 17408 B
  __shared__ alignas(16) __hip_bfloat16 lv[128 * VSTR];         // 18432 B
  __shared__ alignas(16) float sc[TQ * ABSTR];                  // 4352 B
  __shared__ alignas(16) __hip_bfloat16 lp[NHEADS * TQ * PSTR]; // 9216 B

  const int t = threadIdx.x;
  const int lane = t & 63;
  const int h = t >> 6;
  const int n16 = lane & 15;
  const int quad = lane >> 4;
  const int q0 = blockIdx.x * TQ;
  const int split = blockIdx.y;
  const int ksplit = gridDim.y;
  const int tstart = (NTILES_TOTAL * split) / ksplit;
  const int ntiles = (NTILES_TOTAL * (split + 1)) / ksplit - tstart;

  int gqa = q0 + n16; if (gqa >= NQ) gqa = NQ - 1;
  bf16x8 aq = *(const bf16x8*)(Qp + (size_t)gqa * 128 + h * DHEAD + quad * 8);

  const int kr = t >> 2, kc = (t & 3) * 32;
  const int vr = t >> 1, vc = (t & 1) * 32;
  const int e4 = t * 4, qq = e4 >> 6, kkc = e4 & 63;
  int gqe = q0 + qq; if (gqe >= NQ) gqe = NQ - 1;
  const size_t wbase = (size_t)gqe * NKK + kkc;

  // ones B-fragment: col 0 of D = row-sum of A (the softmax denominator)
  bf16x8 bones;
  {
    short one = (short)0x3F80;
    short val = (n16 == 0) ? one : (short)0;
    #pragma unroll
    for (int j = 0; j < 8; ++j) bones[j] = val;
  }

  uint4 pk0, pk1, pk2, pk3, pv0, pv1, pv2, pv3;
  float4 pw; int4 pvs;

  auto issue = [&](int tile) {
    int k0 = (tstart + tile) * TK;
    const uint4* ksrc = (const uint4*)(Kp + (size_t)(k0 + kr) * 128 + kc);
    pk0 = ksrc[0]; pk1 = ksrc[1]; pk2 = ksrc[2]; pk3 = ksrc[3];
    const uint4* vsrc = (const uint4*)(Vt + (size_t)vr * NKK + k0 + vc);
    pv0 = vsrc[0]; pv1 = vsrc[1]; pv2 = vsrc[2]; pv3 = vsrc[3];
    pw  = *(const float4*)(Wl + wbase + k0);
    pvs = *(const int4*)(vis + wbase + k0);
  };
  auto commit = [&]() {
    uint4* kd = (uint4*)&lk[kr * KSTR + kc];
    kd[0] = pk0; kd[1] = pk1; kd[2] = pk2; kd[3] = pk3;
    uint4* vd = (uint4*)&lv[vr * VSTR + vc];
    vd[0] = pv0; vd[1] = pv1; vd[2] = pv2; vd[3] = pv3;
    float4 c4;
    c4.x = pvs.x ? pw.x * CSC : BIGNEG * pw.x;
    c4.y = pvs.y ? pw.y * CSC : BIGNEG * pw.y;
    c4.z = pvs.z ? pw.z * CSC : BIGNEG * pw.z;
    c4.w = pvs.w ? pw.w * CSC : BIGNEG * pw.w;
    *(float4*)&sc[qq * ABSTR + kkc] = c4;
  };

  f32x4 o0 = {0.f, 0.f, 0.f, 0.f};
  f32x4 o1 = {0.f, 0.f, 0.f, 0.f};
  f32x4 o2 = {0.f, 0.f, 0.f, 0.f};   // col 0 = running sum of p per row

  issue(0);
  commit();
  __syncthreads();

  for (int kt = 0; kt < ntiles; ++kt) {
    if (kt + 1 < ntiles) issue(kt + 1);   // loads in flight over compute

    // S = Q K^T (per head)
    f32x4 s[4];
    #pragma unroll
    for (int ks = 0; ks < 4; ++ks) {
      bf16x8 bk = *(const bf16x8*)&lk[(ks * 16 + n16) * KSTR + h * DHEAD + quad * 8];
      f32x4 z = {0.f, 0.f, 0.f, 0.f};
      s[ks] = __builtin_amdgcn_mfma_f32_16x16x32_bf16(aq, bk, z, 0, 0, 0);
    }
    // p = exp2(s*c) (c>=0) or exp2(c) (masked); no reductions needed
    #pragma unroll
    for (int ks = 0; ks < 4; ++ks) {
      #pragma unroll
      for (int r = 0; r < 4; ++r) {
        float c = sc[(quad * 4 + r) * ABSTR + ks * 16 + n16];
        float tt = s[ks][r] * c;
        float arg = (c >= 0.f) ? tt : c;
        float p = exp2f(fminf(arg, 60.f));
        lp[h * (TQ * PSTR) + (quad * 4 + r) * PSTR + ks * 16 + n16] = __float2bfloat16(p);
      }
    }
    // O += P V ; l += P 1 (via ones column)
    #pragma unroll
    for (int kk = 0; kk < 2; ++kk) {
      bf16x8 ap  = *(const bf16x8*)&lp[h * (TQ * PSTR) + n16 * PSTR + kk * 32 + quad * 8];
      bf16x8 bv0 = *(const bf16x8*)&lv[(h * DHEAD + n16) * VSTR + kk * 32 + quad * 8];
      bf16x8 bv1 = *(const bf16x8*)&lv[(h * DHEAD + 16 + n16) * VSTR + kk * 32 + quad * 8];
      o0 = __builtin_amdgcn_mfma_f32_16x16x32_bf16(ap, bv0, o0, 0, 0, 0);
      o1 = __builtin_amdgcn_mfma_f32_16x16x32_bf16(ap, bv1, o1, 0, 0, 0);
      o2 = __builtin_amdgcn_mfma_f32_16x16x32_bf16(ap, bones, o2, 0, 0, 0);
    }

    if (kt + 1 < ntiles) {
      __syncthreads();
      commit();
      __syncthreads();
    }
  }

  // epilogue: unnormalized O + per-head l packed into Opart rows
  #pragma unroll
  for (int r = 0; r < 4; ++r) {
    int gq = q0 + quad * 4 + r;
    if (gq < NQ) {
      float* rowp = Opart + (size_t)split * OSPLIT_F + (size_t)gq * OROW_F;
      rowp[h * DHEAD + n16] = o0[r];
      rowp[h * DHEAD + 16 + n16] = o1[r];
      if (n16 == 0) rowp[128 + h] = o2[r];
    }
  }
}

// ============ merge + proj + preLN + MLP + postLN (MFMA), 8 q/block, 313 blocks ============
// Rows 8..15 of the 16-row MFMA tiles compute clamped-duplicate (finite) values
// and are simply not stored (quad<2 guard) — 2x grid vs 16 q/block.
__global__ __launch_bounds__(256) void mlp_kernel(
    const float* __restrict__ Opart, int ksplit,
    const float* __restrict__ skip,
    const __hip_bfloat16* __restrict__ wball,
    const float* __restrict__ bproj,
    const float* __restrict__ pre_g, const float* __restrict__ pre_b,
    const float* __restrict__ b1, const float* __restrict__ b2,
    const float* __restrict__ post_g, const float* __restrict__ post_b,
    float* __restrict__ out)
{
  __shared__ __hip_bfloat16 sab[16][136];
  __shared__ __hip_bfloat16 znb[16][136];
  __shared__ float znf[16][132];
  __shared__ __hip_bfloat16 hb[16][264];
  __shared__ float part[16][4][2];

  const __hip_bfloat16* wprojb = wball + WPROJB;
  const __hip_bfloat16* w1b    = wball + W1B;
  const __hip_bfloat16* w2b    = wball + W2B;

  const int t = threadIdx.x;
  const int q0 = blockIdx.x * 8;

  // ---- merge k-splits (fixed softmax base: plain sums) ----
  {
    int row = t >> 4, c0 = (t & 15) * 8;
    int gq = q0 + row; int cq = gq < NQ ? gq : NQ - 1;
    int head = c0 >> 5;
    float ll = 0.f;
    float acc8[8] = {};
    for (int s = 0; s < ksplit; ++s) {
      const float* rp = Opart + (size_t)s * OSPLIT_F + (size_t)cq * OROW_F;
      ll += rp[128 + head];
      float4 a = *(const float4*)(rp + c0);
      float4 b = *(const float4*)(rp + c0 + 4);
      acc8[0] += a.x; acc8[1] += a.y; acc8[2] += a.z; acc8[3] += a.w;
      acc8[4] += b.x; acc8[5] += b.y; acc8[6] += b.z; acc8[7] += b.w;
    }
    float rll = 1.f / fmaxf(ll, 1e-30f);
    #pragma unroll
    for (int i = 0; i < 8; ++i)
      sab[row][c0 + i] = __float2bfloat16(acc8[i] * rll);
  }
  __syncthreads();

  const int wid = t >> 6, lane = t & 63;
  const int n16 = lane & 15, quad = lane >> 4;
  const int qrow0 = q0 + quad * 4;

  // ---- GEMM1: proj 128->128 ----
  f32x4 acc1[2] = {};
  for (int kt = 0; kt < 4; ++kt) {
    bf16x8 af = *(const bf16x8*)&sab[n16][kt * 32 + quad * 8];
    #pragma unroll
    for (int ni = 0; ni < 2; ++ni) {
      int o = wid * 32 + ni * 16 + n16;
      bf16x8 bw = *(const bf16x8*)(wprojb + (size_t)o * 128 + kt * 32 + quad * 8);
      acc1[ni] = __builtin_amdgcn_mfma_f32_16x16x32_bf16(af, bw, acc1[ni], 0, 0, 0);
    }
  }
  float z[2][4];
  #pragma unroll
  for (int ni = 0; ni < 2; ++ni) {
    int o = wid * 32 + ni * 16 + n16;
    float bo = bproj[o];
    if (qrow0 + 3 < NQ) {
      float4 sk = *(const float4*)(skip + (size_t)o * NQ + qrow0);
      z[ni][0] = acc1[ni][0] + bo + sk.x;
      z[ni][1] = acc1[ni][1] + bo + sk.y;
      z[ni][2] = acc1[ni][2] + bo + sk.z;
      z[ni][3] = acc1[ni][3] + bo + sk.w;
    } else {
      #pragma unroll
      for (int rg = 0; rg < 4; ++rg) {
        int cq = qrow0 + rg < NQ ? qrow0 + rg : NQ - 1;
        z[ni][rg] = acc1[ni][rg] + bo + skip[(size_t)o * NQ + cq];
      }
    }
  }
  #pragma unroll
  for (int rg = 0; rg < 4; ++rg) {
    float s = z[0][rg] + z[1][rg];
    float ss = z[0][rg] * z[0][rg] + z[1][rg] * z[1][rg];
    s += __shfl_xor(s, 1);  ss += __shfl_xor(ss, 1);
    s += __shfl_xor(s, 2);  ss += __shfl_xor(ss, 2);
    s += __shfl_xor(s, 4);  ss += __shfl_xor(ss, 4);
    s += __shfl_xor(s, 8);  ss += __shfl_xor(ss, 8);
    if (n16 == 0) { part[quad * 4 + rg][wid][0] = s; part[quad * 4 + rg][wid][1] = ss; }
  }
  __syncthreads();
  #pragma unroll
  for (int rg = 0; rg < 4; ++rg) {
    int row = quad * 4 + rg;
    float S  = part[row][0][0] + part[row][1][0] + part[row][2][0] + part[row][3][0];
    float SS = part[row][0][1] + part[row][1][1] + part[row][2][1] + part[row][3][1];
    float mean = S * (1.f / 128.f);
    float var  = SS * (1.f / 128.f) - mean * mean;
    float rstd = rsqrtf(fmaxf(var, 0.f) + 1e-5f);
    #pragma unroll
    for (int ni = 0; ni < 2; ++ni) {
      int o = wid * 32 + ni * 16 + n16;
      float zn = (z[ni][rg] - mean) * rstd * pre_g[o] + pre_b[o];
      znf[row][o] = zn;
      znb[row][o] = __float2bfloat16(zn);
    }
  }
  __syncthreads();

  // ---- GEMM2: 128 -> 256 + GELU ----
  f32x4 acc2[4] = {};
  for (int kt = 0; kt < 4; ++kt) {
    bf16x8 af = *(const bf16x8*)&znb[n16][kt * 32 + quad * 8];
    #pragma unroll
    for (int ni = 0; ni < 4; ++ni) {
      int j = wid * 64 + ni * 16 + n16;
      bf16x8 bw = *(const bf16x8*)(w1b + (size_t)j * 128 + kt * 32 + quad * 8);
      acc2[ni] = __builtin_amdgcn_mfma_f32_16x16x32_bf16(af, bw, acc2[ni], 0, 0, 0);
    }
  }
  #pragma unroll
  for (int ni = 0; ni < 4; ++ni) {
    int j = wid * 64 + ni * 16 + n16;
    float bj = b1[j];
    #pragma unroll
    for (int rg = 0; rg < 4; ++rg) {
      float a1 = acc2[ni][rg] + bj;
      hb[quad * 4 + rg][j] = __float2bfloat16(0.5f * a1 * (1.0f + erff(a1 * 0.70710678118654752f)));
    }
  }
  __syncthreads();

  // ---- GEMM3: 256 -> 128 + residual + postLN ----
  f32x4 acc3[2] = {};
  for (int kt = 0; kt < 8; ++kt) {
    bf16x8 af = *(const bf16x8*)&hb[n16][kt * 32 + quad * 8];
    #pragma unroll
    for (int ni = 0; ni < 2; ++ni) {
      int o = wid * 32 + ni * 16 + n16;
      bf16x8 bw = *(const bf16x8*)(w2b + (size_t)o * 256 + kt * 32 + quad * 8);
      acc3[ni] = __builtin_amdgcn_mfma_f32_16x16x32_bf16(af, bw, acc3[ni], 0, 0, 0);
    }
  }
  float y[2][4];
  #pragma unroll
  for (int ni = 0; ni < 2; ++ni) {
    int o = wid * 32 + ni * 16 + n16;
    float bo = b2[o];
    #pragma unroll
    for (int rg = 0; rg < 4; ++rg)
      y[ni][rg] = znf[quad * 4 + rg][o] + acc3[ni][rg] + bo;
  }
  #pragma unroll
  for (int rg = 0; rg < 4; ++rg) {
    float s = y[0][rg] + y[1][rg];
    float ss = y[0][rg] * y[0][rg] + y[1][rg] * y[1][rg];
    s += __shfl_xor(s, 1);  ss += __shfl_xor(ss, 1);
    s += __shfl_xor(s, 2);  ss += __shfl_xor(ss, 2);
    s += __shfl_xor(s, 4);  ss += __shfl_xor(ss, 4);
    s += __shfl_xor(s, 8);  ss += __shfl_xor(ss, 8);
    if (n16 == 0) { part[quad * 4 + rg][wid][0] = s; part[quad * 4 + rg][wid][1] = ss; }
  }
  __syncthreads();
  #pragma unroll
  for (int rg = 0; rg < 4; ++rg) {
    int row = quad * 4 + rg;
    float S  = part[row][0][0] + part[row][1][0] + part[row][2][0] + part[row][3][0];
    float SS = part[row][0][1] + part[row][1][1] + part[row][2][1] + part[row][3][1];
    float mean = S * (1.f / 128.f);
    float var  = SS * (1.f / 128.f) - mean * mean;
    float rstd = rsqrtf(fmaxf(var, 0.f) + 1e-5f);
    #pragma unroll
    for (int ni = 0; ni < 2; ++ni) {
      int o = wid * 32 + ni * 16 + n16;
      y[ni][rg] = (y[ni][rg] - mean) * rstd * post_g[o] + post_b[o];
    }
  }
  // stores: only rows 0..7 (quad<2) are this block's queries
  if (quad < 2) {
    #pragma unroll
    for (int ni = 0; ni < 2; ++ni) {
      int o = wid * 32 + ni * 16 + n16;
      if (qrow0 + 3 < NQ) {
        *(float4*)(out + (size_t)o * NQ + qrow0) = make_float4(y[ni][0], y[ni][1], y[ni][2], y[ni][3]);
      } else {
        #pragma unroll
        for (int rg = 0; rg < 4; ++rg)
          if (qrow0 + rg < NQ) out[(size_t)o * NQ + qrow0 + rg] = y[ni][rg];
      }
    }
  }
}

extern "C" void kernel_launch(void* const* d_in, const int* in_sizes, int n_in,
                              void* d_out, int out_size, void* d_ws, size_t ws_size,
                              hipStream_t stream) {
  if (ws_size < WS_REQ3) return;  // fail-safe (clean zero output)
  const int ksplit = (ws_size >= WS_REQ6) ? 6 : (ws_size >= WS_REQ4) ? 4 : 3;

  const float* q     = (const float*)d_in[0];
  const float* k     = (const float*)d_in[1];
  const float* v     = (const float*)d_in[2];
  const float* Wl    = (const float*)d_in[3];
  const int*   vis   = (const int*)d_in[4];
  const float* skip  = (const float*)d_in[5];
  const float* qn_g  = (const float*)d_in[6];
  const float* qn_b  = (const float*)d_in[7];
  const float* kn_g  = (const float*)d_in[8];
  const float* kn_b  = (const float*)d_in[9];
  const float* vn_g  = (const float*)d_in[10];
  const float* vn_b  = (const float*)d_in[11];
  const float* wq    = (const float*)d_in[12];
  const float* bq    = (const float*)d_in[13];
  const float* wk    = (const float*)d_in[14];
  const float* bk    = (const float*)d_in[15];
  const float* wv    = (const float*)d_in[16];
  const float* bv    = (const float*)d_in[17];
  const float* wproj = (const float*)d_in[18];
  const float* bproj = (const float*)d_in[19];
  const float* pre_g = (const float*)d_in[20];
  const float* pre_b = (const float*)d_in[21];
  const float* w1    = (const float*)d_in[22];
  const float* b1    = (const float*)d_in[23];
  const float* w2    = (const float*)d_in[24];
  const float* b2    = (const float*)d_in[25];
  const float* post_g= (const float*)d_in[26];
  const float* post_b= (const float*)d_in[27];

  char* ws = (char*)d_ws;
  __hip_bfloat16* Qp = (__hip_bfloat16*)(ws + WS_QP);
  __hip_bfloat16* Kp = (__hip_bfloat16*)(ws + WS_KP);
  __hip_bfloat16* Vt = (__hip_bfloat16*)(ws + WS_VT);
  __hip_bfloat16* Wb = (__hip_bfloat16*)(ws + WS_WB);
  float* Opart = (float*)(ws + WS_OP);

  hipLaunchKernelGGL(wconv_kernel, dim3(128), dim3(256), 0, stream,
                     wq, wk, wv, wproj, w1, w2, Wb);

  hipLaunchKernelGGL(lnproj_kernel, dim3(475), dim3(256), 0, stream,
                     q, k, v, qn_g, qn_b, kn_g, kn_b, vn_g, vn_b,
                     Wb, bq, bk, bv, Qp, Kp, Vt);

  hipLaunchKernelGGL(attn_kernel, dim3(QBLOCKS, ksplit), dim3(256), 0, stream,
                     Qp, Kp, Vt, Wl, vis, Opart);

  hipLaunchKernelGGL(mlp_kernel, dim3(MQBLOCKS), dim3(256), 0, stream,
                     Opart, ksplit, skip, Wb, bproj, pre_g, pre_b,
                     b1, b2, post_g, post_b, (float*)d_out);
}

// Round 9
// 249.180 us; speedup vs baseline: 1.0968x; 1.0968x over previous
//
#include <hip/hip_runtime.h>
#include <hip/hip_bf16.h>

typedef __attribute__((ext_vector_type(8))) short bf16x8;
typedef __attribute__((ext_vector_type(4))) float f32x4;

#define NQ 2500
#define NKK 6336
#define NHEADS 4
#define DHEAD 32
// SCALE * log2(e): p = exp2(s * c)
#define CSC 0.25503482f
#define BIGNEG (-1.0e30f)

// workspace byte offsets
#define WS_QP 0
#define WS_KP 640000
#define WS_VT 2262016
#define WS_WB 3884032
#define WS_OP 4146176
// Opart: per split 2500 rows x 136 floats (128 O + 4 l per head)
#define OSPLIT_F 340000
#define OROW_F 136
#define WS_REQ3 8226176ULL
#define WS_REQ4 9586176ULL
#define WS_REQ6 12306176ULL

// bf16 weight element offsets inside WS_WB
#define WQB 0
#define WKB 16384
#define WVB 32768
#define WPROJB 49152
#define W1B 65536
#define W2B 98304

#define NTILES_TOTAL 99
#define TQ 16
#define ATQ 32
#define TK 64
#define QBLOCKS 157
#define AQBLOCKS 79

#define KSTR 136
#define VSTR 72
#define PSTR 72
#define ABSTR 68

__device__ __forceinline__ unsigned short bf16bits(float x) {
  union { __hip_bfloat16 h; unsigned short s; } cv;
  cv.h = __float2bfloat16(x);
  return cv.s;
}

// ============ weight fp32->bf16 conversion (once per launch) ============
__global__ __launch_bounds__(256) void wconv_kernel(
    const float* __restrict__ wq, const float* __restrict__ wk,
    const float* __restrict__ wv, const float* __restrict__ wproj,
    const float* __restrict__ w1, const float* __restrict__ w2,
    __hip_bfloat16* __restrict__ wb)
{
  int e = (blockIdx.x * 256 + threadIdx.x) * 4;
  const float* src; int off;
  if (e < 16384)      { src = wq;    off = e; }
  else if (e < 32768) { src = wk;    off = e - 16384; }
  else if (e < 49152) { src = wv;    off = e - 32768; }
  else if (e < 65536) { src = wproj; off = e - 49152; }
  else if (e < 98304) { src = w1;    off = e - 65536; }
  else                { src = w2;    off = e - 98304; }
  float4 v = *(const float4*)(src + off);
  ushort4 o4;
  o4.x = bf16bits(v.x); o4.y = bf16bits(v.y); o4.z = bf16bits(v.z); o4.w = bf16bits(v.w);
  *(ushort4*)((unsigned short*)wb + e) = o4;
}

// ============ lnproj: LN + 128x128 projection (MFMA), 32 rows/block, 256 thr ============
__global__ __launch_bounds__(256) void lnproj_kernel(
    const float* __restrict__ qin, const float* __restrict__ kin, const float* __restrict__ vin,
    const float* __restrict__ qn_g, const float* __restrict__ qn_b,
    const float* __restrict__ kn_g, const float* __restrict__ kn_b,
    const float* __restrict__ vn_g, const float* __restrict__ vn_b,
    const __hip_bfloat16* __restrict__ wball,
    const float* __restrict__ bq, const float* __restrict__ bk, const float* __restrict__ bv,
    __hip_bfloat16* __restrict__ Qp, __hip_bfloat16* __restrict__ Kp,
    __hip_bfloat16* __restrict__ Vt)
{
  __shared__ __hip_bfloat16 lxb[32][136];
  __shared__ float lpart[32][8][2];
  __shared__ float lmr[32][2];
  __shared__ float lgb[128], lbeb[128];

  const int t = threadIdx.x;
  const int bb = blockIdx.x;
  int mode, row0;
  const float *in, *g, *be, *bo;
  const __hip_bfloat16* wb;
  if (bb < 79)       { mode = 0; row0 = bb * 32;         in = qin; g = qn_g; be = qn_b; wb = wball + WQB; bo = bq; }
  else if (bb < 277) { mode = 1; row0 = (bb - 79) * 32;  in = kin; g = kn_g; be = kn_b; wb = wball + WKB; bo = bk; }
  else               { mode = 2; row0 = (bb - 277) * 32; in = vin; g = vn_g; be = vn_b; wb = wball + WVB; bo = bv; }

  if (t < 128) { lgb[t] = g[t]; lbeb[t] = be[t]; }

  const int row = t & 31, seg = t >> 5;   // 8 segs x 16 d each
  int grow = row0 + row;
  size_t base, dstr;
  bool rvalid = true;
  if (mode == 0) { rvalid = (grow < NQ); base = (size_t)(rvalid ? grow : NQ - 1); dstr = NQ; }
  else { int n = grow / 1056, rr = grow - n * 1056; base = (size_t)n * 135168 + rr; dstr = 1056; }

  float xr[16];
  float s = 0.f, ss = 0.f;
  #pragma unroll
  for (int i = 0; i < 16; ++i) {
    float x = in[base + (size_t)(seg * 16 + i) * dstr];
    xr[i] = x; s += x; ss += x * x;
  }
  lpart[row][seg][0] = s; lpart[row][seg][1] = ss;
  __syncthreads();
  if (t < 32) {
    float S = 0.f, SS = 0.f;
    #pragma unroll
    for (int j = 0; j < 8; ++j) { S += lpart[t][j][0]; SS += lpart[t][j][1]; }
    float mean = S * (1.f / 128.f);
    float var  = SS * (1.f / 128.f) - mean * mean;
    lmr[t][0] = mean;
    lmr[t][1] = rsqrtf(fmaxf(var, 0.f) + 1e-5f);
  }
  __syncthreads();
  {
    float mean = lmr[row][0], rstd = lmr[row][1];
    #pragma unroll
    for (int i = 0; i < 16; ++i) {
      int d = seg * 16 + i;
      lxb[row][d] = __float2bfloat16((xr[i] - mean) * rstd * lgb[d] + lbeb[d]);
    }
  }
  __syncthreads();

  // GEMM: 32 rows x 128 out, K=128; 4 waves, each 32-wide o-chunk
  const int wid = t >> 6, lane = t & 63;
  const int n16 = lane & 15, quad = lane >> 4;
  const int ow = wid * 32;

  f32x4 acc[2][2] = {};
  for (int kt = 0; kt < 4; ++kt) {
    bf16x8 af[2];
    #pragma unroll
    for (int mi = 0; mi < 2; ++mi)
      af[mi] = *(const bf16x8*)&lxb[mi * 16 + n16][kt * 32 + quad * 8];
    #pragma unroll
    for (int ni = 0; ni < 2; ++ni) {
      bf16x8 bw = *(const bf16x8*)(wb + (size_t)(ow + ni * 16 + n16) * 128 + kt * 32 + quad * 8);
      #pragma unroll
      for (int mi = 0; mi < 2; ++mi)
        acc[mi][ni] = __builtin_amdgcn_mfma_f32_16x16x32_bf16(af[mi], bw, acc[mi][ni], 0, 0, 0);
    }
  }

  float bias[2];
  #pragma unroll
  for (int ni = 0; ni < 2; ++ni) bias[ni] = bo[ow + ni * 16 + n16];

  #pragma unroll
  for (int mi = 0; mi < 2; ++mi) {
    int gr0 = row0 + mi * 16 + quad * 4;
    if (mode == 2) {
      #pragma unroll
      for (int ni = 0; ni < 2; ++ni) {
        int o = ow + ni * 16 + n16;
        ushort4 v4;
        v4.x = bf16bits(acc[mi][ni][0] + bias[ni]);
        v4.y = bf16bits(acc[mi][ni][1] + bias[ni]);
        v4.z = bf16bits(acc[mi][ni][2] + bias[ni]);
        v4.w = bf16bits(acc[mi][ni][3] + bias[ni]);
        *(ushort4*)((unsigned short*)Vt + (size_t)o * NKK + gr0) = v4;
      }
    } else {
      #pragma unroll
      for (int rg = 0; rg < 4; ++rg) {
        int gr = gr0 + rg;
        if (mode != 0 || gr < NQ) {
          #pragma unroll
          for (int ni = 0; ni < 2; ++ni) {
            int o = ow + ni * 16 + n16;
            __hip_bfloat16 b16 = __float2bfloat16(acc[mi][ni][rg] + bias[ni]);
            if (mode == 0) Qp[(size_t)gr * 128 + o] = b16;
            else           Kp[(size_t)gr * 128 + o] = b16;
          }
        }
      }
    }
  }
}

// ============ flash attention: TQ=32 (2 q-subtiles/wave), fixed-base softmax ============
// Halves K/V L2 re-read traffic vs TQ=16 and doubles MFMA per staged tile.
__global__ __launch_bounds__(256, 2) void attn_kernel(
    const __hip_bfloat16* __restrict__ Qp,
    const __hip_bfloat16* __restrict__ Kp,
    const __hip_bfloat16* __restrict__ Vt,
    const float* __restrict__ Wl,
    const int* __restrict__ vis,
    float* __restrict__ Opart)
{
  __shared__ alignas(16) __hip_bfloat16 lk[TK * KSTR];           // 17408 B
  __shared__ alignas(16) __hip_bfloat16 lv[128 * VSTR];          // 18432 B
  __shared__ alignas(16) float sc[ATQ * ABSTR];                  // 8704 B
  __shared__ alignas(16) __hip_bfloat16 lp[NHEADS * ATQ * PSTR]; // 18432 B

  const int t = threadIdx.x;
  const int lane = t & 63;
  const int h = t >> 6;
  const int n16 = lane & 15;
  const int quad = lane >> 4;
  const int q0 = blockIdx.x * ATQ;
  const int split = blockIdx.y;
  const int ksplit = gridDim.y;
  const int tstart = (NTILES_TOTAL * split) / ksplit;
  const int ntiles = (NTILES_TOTAL * (split + 1)) / ksplit - tstart;

  bf16x8 aq[2];
  #pragma unroll
  for (int m = 0; m < 2; ++m) {
    int gqa = q0 + m * 16 + n16; if (gqa >= NQ) gqa = NQ - 1;
    aq[m] = *(const bf16x8*)(Qp + (size_t)gqa * 128 + h * DHEAD + quad * 8);
  }

  const int kr = t >> 2, kc = (t & 3) * 32;
  const int vr = t >> 1, vc = (t & 1) * 32;
  const int qq = t >> 3, kkc = (t & 7) * 8;   // W/vis: 8 elems/thread, 32 rows
  int gqe = q0 + qq; if (gqe >= NQ) gqe = NQ - 1;
  const size_t wbase = (size_t)gqe * NKK + kkc;

  // ones B-fragment: col 0 of D = row-sum of A (the softmax denominator)
  bf16x8 bones;
  {
    short one = (short)0x3F80;
    short val = (n16 == 0) ? one : (short)0;
    #pragma unroll
    for (int j = 0; j < 8; ++j) bones[j] = val;
  }

  uint4 pk0, pk1, pk2, pk3, pv0, pv1, pv2, pv3;
  float4 pw0, pw1; int4 pvs0, pvs1;

  auto issue = [&](int tile) {
    int k0 = (tstart + tile) * TK;
    const uint4* ksrc = (const uint4*)(Kp + (size_t)(k0 + kr) * 128 + kc);
    pk0 = ksrc[0]; pk1 = ksrc[1]; pk2 = ksrc[2]; pk3 = ksrc[3];
    const uint4* vsrc = (const uint4*)(Vt + (size_t)vr * NKK + k0 + vc);
    pv0 = vsrc[0]; pv1 = vsrc[1]; pv2 = vsrc[2]; pv3 = vsrc[3];
    pw0  = *(const float4*)(Wl + wbase + k0);
    pw1  = *(const float4*)(Wl + wbase + k0 + 4);
    pvs0 = *(const int4*)(vis + wbase + k0);
    pvs1 = *(const int4*)(vis + wbase + k0 + 4);
  };
  auto commit = [&]() {
    uint4* kd = (uint4*)&lk[kr * KSTR + kc];
    kd[0] = pk0; kd[1] = pk1; kd[2] = pk2; kd[3] = pk3;
    uint4* vd = (uint4*)&lv[vr * VSTR + vc];
    vd[0] = pv0; vd[1] = pv1; vd[2] = pv2; vd[3] = pv3;
    float4 c0, c1;
    c0.x = pvs0.x ? pw0.x * CSC : BIGNEG * pw0.x;
    c0.y = pvs0.y ? pw0.y * CSC : BIGNEG * pw0.y;
    c0.z = pvs0.z ? pw0.z * CSC : BIGNEG * pw0.z;
    c0.w = pvs0.w ? pw0.w * CSC : BIGNEG * pw0.w;
    c1.x = pvs1.x ? pw1.x * CSC : BIGNEG * pw1.x;
    c1.y = pvs1.y ? pw1.y * CSC : BIGNEG * pw1.y;
    c1.z = pvs1.z ? pw1.z * CSC : BIGNEG * pw1.z;
    c1.w = pvs1.w ? pw1.w * CSC : BIGNEG * pw1.w;
    *(float4*)&sc[qq * ABSTR + kkc] = c0;
    *(float4*)&sc[qq * ABSTR + kkc + 4] = c1;
  };

  f32x4 o[2][3];
  #pragma unroll
  for (int m = 0; m < 2; ++m)
    #pragma unroll
    for (int j = 0; j < 3; ++j)
      o[m][j] = f32x4{0.f, 0.f, 0.f, 0.f};

  issue(0);
  commit();
  __syncthreads();

  for (int kt = 0; kt < ntiles; ++kt) {
    if (kt + 1 < ntiles) issue(kt + 1);   // loads in flight over compute

    // S = Q K^T: K-fragments shared across both q-subtiles
    f32x4 s[2][4];
    #pragma unroll
    for (int ks = 0; ks < 4; ++ks) {
      bf16x8 bk = *(const bf16x8*)&lk[(ks * 16 + n16) * KSTR + h * DHEAD + quad * 8];
      f32x4 z = {0.f, 0.f, 0.f, 0.f};
      s[0][ks] = __builtin_amdgcn_mfma_f32_16x16x32_bf16(aq[0], bk, z, 0, 0, 0);
      s[1][ks] = __builtin_amdgcn_mfma_f32_16x16x32_bf16(aq[1], bk, z, 0, 0, 0);
    }
    // p = exp2(s*c) (c>=0) or exp2(c) (masked)
    #pragma unroll
    for (int m = 0; m < 2; ++m) {
      #pragma unroll
      for (int ks = 0; ks < 4; ++ks) {
        #pragma unroll
        for (int r = 0; r < 4; ++r) {
          int row = m * 16 + quad * 4 + r;
          float c = sc[row * ABSTR + ks * 16 + n16];
          float tt = s[m][ks][r] * c;
          float arg = (c >= 0.f) ? tt : c;
          float p = exp2f(fminf(arg, 60.f));
          lp[h * (ATQ * PSTR) + row * PSTR + ks * 16 + n16] = __float2bfloat16(p);
        }
      }
    }
    // O += P V ; l += P 1 (V fragments shared across both q-subtiles)
    #pragma unroll
    for (int kk = 0; kk < 2; ++kk) {
      bf16x8 bv0 = *(const bf16x8*)&lv[(h * DHEAD + n16) * VSTR + kk * 32 + quad * 8];
      bf16x8 bv1 = *(const bf16x8*)&lv[(h * DHEAD + 16 + n16) * VSTR + kk * 32 + quad * 8];
      #pragma unroll
      for (int m = 0; m < 2; ++m) {
        bf16x8 ap = *(const bf16x8*)&lp[h * (ATQ * PSTR) + (m * 16 + n16) * PSTR + kk * 32 + quad * 8];
        o[m][0] = __builtin_amdgcn_mfma_f32_16x16x32_bf16(ap, bv0, o[m][0], 0, 0, 0);
        o[m][1] = __builtin_amdgcn_mfma_f32_16x16x32_bf16(ap, bv1, o[m][1], 0, 0, 0);
        o[m][2] = __builtin_amdgcn_mfma_f32_16x16x32_bf16(ap, bones, o[m][2], 0, 0, 0);
      }
    }

    if (kt + 1 < ntiles) {
      __syncthreads();
      commit();
      __syncthreads();
    }
  }

  // epilogue: unnormalized O + per-head l packed into Opart rows
  #pragma unroll
  for (int m = 0; m < 2; ++m) {
    #pragma unroll
    for (int r = 0; r < 4; ++r) {
      int gq = q0 + m * 16 + quad * 4 + r;
      if (gq < NQ) {
        float* rowp = Opart + (size_t)split * OSPLIT_F + (size_t)gq * OROW_F;
        rowp[h * DHEAD + n16] = o[m][0][r];
        rowp[h * DHEAD + 16 + n16] = o[m][1][r];
        if (n16 == 0) rowp[128 + h] = o[m][2][r];
      }
    }
  }
}

// ============ merge + proj + preLN + MLP + postLN (MFMA), 16 q/block ============
__global__ __launch_bounds__(256) void mlp_kernel(
    const float* __restrict__ Opart, int ksplit,
    const float* __restrict__ skip,
    const __hip_bfloat16* __restrict__ wball,
    const float* __restrict__ bproj,
    const float* __restrict__ pre_g, const float* __restrict__ pre_b,
    const float* __restrict__ b1, const float* __restrict__ b2,
    const float* __restrict__ post_g, const float* __restrict__ post_b,
    float* __restrict__ out)
{
  __shared__ __hip_bfloat16 sab[16][136];
  __shared__ __hip_bfloat16 znb[16][136];
  __shared__ float znf[16][132];
  __shared__ __hip_bfloat16 hb[16][264];
  __shared__ float part[16][4][2];

  const __hip_bfloat16* wprojb = wball + WPROJB;
  const __hip_bfloat16* w1b    = wball + W1B;
  const __hip_bfloat16* w2b    = wball + W2B;

  const int t = threadIdx.x;
  const int q0 = blockIdx.x * TQ;

  // ---- merge k-splits (fixed softmax base: plain sums) ----
  {
    int row = t >> 4, c0 = (t & 15) * 8;
    int gq = q0 + row; int cq = gq < NQ ? gq : NQ - 1;
    int head = c0 >> 5;
    float ll = 0.f;
    float acc8[8] = {};
    for (int s = 0; s < ksplit; ++s) {
      const float* rp = Opart + (size_t)s * OSPLIT_F + (size_t)cq * OROW_F;
      ll += rp[128 + head];
      float4 a = *(const float4*)(rp + c0);
      float4 b = *(const float4*)(rp + c0 + 4);
      acc8[0] += a.x; acc8[1] += a.y; acc8[2] += a.z; acc8[3] += a.w;
      acc8[4] += b.x; acc8[5] += b.y; acc8[6] += b.z; acc8[7] += b.w;
    }
    float rll = 1.f / fmaxf(ll, 1e-30f);
    #pragma unroll
    for (int i = 0; i < 8; ++i)
      sab[row][c0 + i] = __float2bfloat16(acc8[i] * rll);
  }
  __syncthreads();

  const int wid = t >> 6, lane = t & 63;
  const int n16 = lane & 15, quad = lane >> 4;
  const int qrow0 = q0 + quad * 4;

  // ---- GEMM1: proj 128->128 ----
  f32x4 acc1[2] = {};
  for (int kt = 0; kt < 4; ++kt) {
    bf16x8 af = *(const bf16x8*)&sab[n16][kt * 32 + quad * 8];
    #pragma unroll
    for (int ni = 0; ni < 2; ++ni) {
      int o = wid * 32 + ni * 16 + n16;
      bf16x8 bw = *(const bf16x8*)(wprojb + (size_t)o * 128 + kt * 32 + quad * 8);
      acc1[ni] = __builtin_amdgcn_mfma_f32_16x16x32_bf16(af, bw, acc1[ni], 0, 0, 0);
    }
  }
  float z[2][4];
  #pragma unroll
  for (int ni = 0; ni < 2; ++ni) {
    int o = wid * 32 + ni * 16 + n16;
    float bo = bproj[o];
    if (qrow0 + 3 < NQ) {
      float4 sk = *(const float4*)(skip + (size_t)o * NQ + qrow0);
      z[ni][0] = acc1[ni][0] + bo + sk.x;
      z[ni][1] = acc1[ni][1] + bo + sk.y;
      z[ni][2] = acc1[ni][2] + bo + sk.z;
      z[ni][3] = acc1[ni][3] + bo + sk.w;
    } else {
      #pragma unroll
      for (int rg = 0; rg < 4; ++rg) {
        int cq = qrow0 + rg < NQ ? qrow0 + rg : NQ - 1;
        z[ni][rg] = acc1[ni][rg] + bo + skip[(size_t)o * NQ + cq];
      }
    }
  }
  #pragma unroll
  for (int rg = 0; rg < 4; ++rg) {
    float s = z[0][rg] + z[1][rg];
    float ss = z[0][rg] * z[0][rg] + z[1][rg] * z[1][rg];
    s += __shfl_xor(s, 1);  ss += __shfl_xor(ss, 1);
    s += __shfl_xor(s, 2);  ss += __shfl_xor(ss, 2);
    s += __shfl_xor(s, 4);  ss += __shfl_xor(ss, 4);
    s += __shfl_xor(s, 8);  ss += __shfl_xor(ss, 8);
    if (n16 == 0) { part[quad * 4 + rg][wid][0] = s; part[quad * 4 + rg][wid][1] = ss; }
  }
  __syncthreads();
  #pragma unroll
  for (int rg = 0; rg < 4; ++rg) {
    int row = quad * 4 + rg;
    float S  = part[row][0][0] + part[row][1][0] + part[row][2][0] + part[row][3][0];
    float SS = part[row][0][1] + part[row][1][1] + part[row][2][1] + part[row][3][1];
    float mean = S * (1.f / 128.f);
    float var  = SS * (1.f / 128.f) - mean * mean;
    float rstd = rsqrtf(fmaxf(var, 0.f) + 1e-5f);
    #pragma unroll
    for (int ni = 0; ni < 2; ++ni) {
      int o = wid * 32 + ni * 16 + n16;
      float zn = (z[ni][rg] - mean) * rstd * pre_g[o] + pre_b[o];
      znf[row][o] = zn;
      znb[row][o] = __float2bfloat16(zn);
    }
  }
  __syncthreads();

  // ---- GEMM2: 128 -> 256 + GELU ----
  f32x4 acc2[4] = {};
  for (int kt = 0; kt < 4; ++kt) {
    bf16x8 af = *(const bf16x8*)&znb[n16][kt * 32 + quad * 8];
    #pragma unroll
    for (int ni = 0; ni < 4; ++ni) {
      int j = wid * 64 + ni * 16 + n16;
      bf16x8 bw = *(const bf16x8*)(w1b + (size_t)j * 128 + kt * 32 + quad * 8);
      acc2[ni] = __builtin_amdgcn_mfma_f32_16x16x32_bf16(af, bw, acc2[ni], 0, 0, 0);
    }
  }
  #pragma unroll
  for (int ni = 0; ni < 4; ++ni) {
    int j = wid * 64 + ni * 16 + n16;
    float bj = b1[j];
    #pragma unroll
    for (int rg = 0; rg < 4; ++rg) {
      float a1 = acc2[ni][rg] + bj;
      hb[quad * 4 + rg][j] = __float2bfloat16(0.5f * a1 * (1.0f + erff(a1 * 0.70710678118654752f)));
    }
  }
  __syncthreads();

  // ---- GEMM3: 256 -> 128 + residual + postLN ----
  f32x4 acc3[2] = {};
  for (int kt = 0; kt < 8; ++kt) {
    bf16x8 af = *(const bf16x8*)&hb[n16][kt * 32 + quad * 8];
    #pragma unroll
    for (int ni = 0; ni < 2; ++ni) {
      int o = wid * 32 + ni * 16 + n16;
      bf16x8 bw = *(const bf16x8*)(w2b + (size_t)o * 256 + kt * 32 + quad * 8);
      acc3[ni] = __builtin_amdgcn_mfma_f32_16x16x32_bf16(af, bw, acc3[ni], 0, 0, 0);
    }
  }
  float y[2][4];
  #pragma unroll
  for (int ni = 0; ni < 2; ++ni) {
    int o = wid * 32 + ni * 16 + n16;
    float bo = b2[o];
    #pragma unroll
    for (int rg = 0; rg < 4; ++rg)
      y[ni][rg] = znf[quad * 4 + rg][o] + acc3[ni][rg] + bo;
  }
  #pragma unroll
  for (int rg = 0; rg < 4; ++rg) {
    float s = y[0][rg] + y[1][rg];
    float ss = y[0][rg] * y[0][rg] + y[1][rg] * y[1][rg];
    s += __shfl_xor(s, 1);  ss += __shfl_xor(ss, 1);
    s += __shfl_xor(s, 2);  ss += __shfl_xor(ss, 2);
    s += __shfl_xor(s, 4);  ss += __shfl_xor(ss, 4);
    s += __shfl_xor(s, 8);  ss += __shfl_xor(ss, 8);
    if (n16 == 0) { part[quad * 4 + rg][wid][0] = s; part[quad * 4 + rg][wid][1] = ss; }
  }
  __syncthreads();
  #pragma unroll
  for (int rg = 0; rg < 4; ++rg) {
    int row = quad * 4 + rg;
    float S  = part[row][0][0] + part[row][1][0] + part[row][2][0] + part[row][3][0];
    float SS = part[row][0][1] + part[row][1][1] + part[row][2][1] + part[row][3][1];
    float mean = S * (1.f / 128.f);
    float var  = SS * (1.f / 128.f) - mean * mean;
    float rstd = rsqrtf(fmaxf(var, 0.f) + 1e-5f);
    #pragma unroll
    for (int ni = 0; ni < 2; ++ni) {
      int o = wid * 32 + ni * 16 + n16;
      y[ni][rg] = (y[ni][rg] - mean) * rstd * post_g[o] + post_b[o];
    }
  }
  #pragma unroll
  for (int ni = 0; ni < 2; ++ni) {
    int o = wid * 32 + ni * 16 + n16;
    if (qrow0 + 3 < NQ) {
      *(float4*)(out + (size_t)o * NQ + qrow0) = make_float4(y[ni][0], y[ni][1], y[ni][2], y[ni][3]);
    } else {
      #pragma unroll
      for (int rg = 0; rg < 4; ++rg)
        if (qrow0 + rg < NQ) out[(size_t)o * NQ + qrow0 + rg] = y[ni][rg];
    }
  }
}

extern "C" void kernel_launch(void* const* d_in, const int* in_sizes, int n_in,
                              void* d_out, int out_size, void* d_ws, size_t ws_size,
                              hipStream_t stream) {
  if (ws_size < WS_REQ3) return;  // fail-safe (clean zero output)
  const int ksplit = (ws_size >= WS_REQ6) ? 6 : (ws_size >= WS_REQ4) ? 4 : 3;

  const float* q     = (const float*)d_in[0];
  const float* k     = (const float*)d_in[1];
  const float* v     = (const float*)d_in[2];
  const float* Wl    = (const float*)d_in[3];
  const int*   vis   = (const int*)d_in[4];
  const float* skip  = (const float*)d_in[5];
  const float* qn_g  = (const float*)d_in[6];
  const float* qn_b  = (const float*)d_in[7];
  const float* kn_g  = (const float*)d_in[8];
  const float* kn_b  = (const float*)d_in[9];
  const float* vn_g  = (const float*)d_in[10];
  const float* vn_b  = (const float*)d_in[11];
  const float* wq    = (const float*)d_in[12];
  const float* bq    = (const float*)d_in[13];
  const float* wk    = (const float*)d_in[14];
  const float* bk    = (const float*)d_in[15];
  const float* wv    = (const float*)d_in[16];
  const float* bv    = (const float*)d_in[17];
  const float* wproj = (const float*)d_in[18];
  const float* bproj = (const float*)d_in[19];
  const float* pre_g = (const float*)d_in[20];
  const float* pre_b = (const float*)d_in[21];
  const float* w1    = (const float*)d_in[22];
  const float* b1    = (const float*)d_in[23];
  const float* w2    = (const float*)d_in[24];
  const float* b2    = (const float*)d_in[25];
  const float* post_g= (const float*)d_in[26];
  const float* post_b= (const float*)d_in[27];

  char* ws = (char*)d_ws;
  __hip_bfloat16* Qp = (__hip_bfloat16*)(ws + WS_QP);
  __hip_bfloat16* Kp = (__hip_bfloat16*)(ws + WS_KP);
  __hip_bfloat16* Vt = (__hip_bfloat16*)(ws + WS_VT);
  __hip_bfloat16* Wb = (__hip_bfloat16*)(ws + WS_WB);
  float* Opart = (float*)(ws + WS_OP);

  hipLaunchKernelGGL(wconv_kernel, dim3(128), dim3(256), 0, stream,
                     wq, wk, wv, wproj, w1, w2, Wb);

  hipLaunchKernelGGL(lnproj_kernel, dim3(475), dim3(256), 0, stream,
                     q, k, v, qn_g, qn_b, kn_g, kn_b, vn_g, vn_b,
                     Wb, bq, bk, bv, Qp, Kp, Vt);

  hipLaunchKernelGGL(attn_kernel, dim3(AQBLOCKS, ksplit), dim3(256), 0, stream,
                     Qp, Kp, Vt, Wl, vis, Opart);

  hipLaunchKernelGGL(mlp_kernel, dim3(QBLOCKS), dim3(256), 0, stream,
                     Opart, ksplit, skip, Wb, bproj, pre_g, pre_b,
                     b1, b2, post_g, post_b, (float*)d_out);
}